// Round 11
// baseline (86.870 us; speedup 1.0000x reference)
//
#include <hip/hip_runtime.h>
#include <math.h>

typedef float f32x2 __attribute__((ext_vector_type(2)));

#define TWO_PI 6.283185307179586f
#define SMOOTH 0.1f
#define SPW 8                  // stations per WAVE
#define WAVES 4
#define BLOCK 256
#define SPB (SPW * WAVES)      // 32 stations per block
#define NPAIR 3                // column pairs per thread

__device__ __forceinline__ f32x2 sp2(float x) { f32x2 r; r.x = x; r.y = x; return r; }
__device__ __forceinline__ void store8(float* p, f32x2 v) { __builtin_memcpy(p, &v, 8); }
__device__ __forceinline__ float rlane(float v, int l) {
    return __uint_as_float((unsigned)__builtin_amdgcn_readlane((int)__float_as_uint(v), l));
}

// v10 = v5 (R6, 40.3us) + SLOPE EXPERIMENT: optionally write the identical
// 146 MB signal a second time into d_ws (different pages -> genuine extra HBM
// write traffic, same store pattern). The marginal cost of the second pass
// separates "fixed per-replay overhead + full-BW writes" from "true ~3.6 TB/s
// write BW" — the two surviving theories after 6 store-shape falsifications.
__global__ __launch_bounds__(BLOCK) void fused_v10(
    const float* __restrict__ time_vector,
    const float* __restrict__ constant_offset,
    const float* __restrict__ linear_trend,
    const float* __restrict__ amps,      // [N][4]
    const float* __restrict__ phs,       // [N][4]
    const float* __restrict__ wgt,       // [N][K]
    const float* __restrict__ periods,   // [4]
    const int*   __restrict__ nbidx,     // [N][K]
    float* __restrict__ out,             // [N][T]
    float* __restrict__ ws,              // scratch mirror (slope probe)
    int N, int T, int K, int dw)
{
    const int tid   = threadIdx.x;
    const int wave  = tid >> 6;
    const int lane  = tid & 63;
    const int wbase = blockIdx.x * SPB + wave * SPW;

    if (wbase >= N) return;
    int send = N - wbase; if (send > SPW) send = SPW;

    // ---- Phase 1: all lanes compute coefs of station wbase+(lane&7) ----
    int sid = wbase + (lane & (SPW - 1));
    if (sid >= N) sid = N - 1;

    float4 a = reinterpret_cast<const float4*>(amps)[sid];
    float4 p = reinterpret_cast<const float4*>(phs)[sid];

    int   nb[5]; float w[5];
    __builtin_memcpy(nb, nbidx + (size_t)sid * K, 5 * sizeof(int));
    __builtin_memcpy(w,  wgt   + (size_t)sid * K, 5 * sizeof(float));

    float av0 = 0.f, av1 = 0.f, av2 = 0.f, av3 = 0.f;
    float pv0 = 0.f, pv1 = 0.f, pv2 = 0.f, pv3 = 0.f;
    #pragma unroll
    for (int k = 0; k < 5; ++k) {
        float4 na = reinterpret_cast<const float4*>(amps)[nb[k]];
        float4 np = reinterpret_cast<const float4*>(phs)[nb[k]];
        av0 += w[k] * na.x; av1 += w[k] * na.y; av2 += w[k] * na.z; av3 += w[k] * na.w;
        pv0 += w[k] * np.x; pv1 += w[k] * np.y; pv2 += w[k] * np.z; pv3 += w[k] * np.w;
    }
    float sa0 = (1.0f - SMOOTH) * a.x + SMOOTH * av0;
    float sa1 = (1.0f - SMOOTH) * a.y + SMOOTH * av1;
    float sa2 = (1.0f - SMOOTH) * a.z + SMOOTH * av2;
    float sa3 = (1.0f - SMOOTH) * a.w + SMOOTH * av3;
    float sp0 = (1.0f - SMOOTH) * p.x + SMOOTH * pv0;
    float sp1 = (1.0f - SMOOTH) * p.y + SMOOTH * pv1;
    float sp2v = (1.0f - SMOOTH) * p.z + SMOOTH * pv2;
    float sp3 = (1.0f - SMOOTH) * p.w + SMOOTH * pv3;

    float cc = constant_offset[sid];
    float cm = linear_trend[sid];
    float cA0 = sa0 * __cosf(sp0),  cB0 = sa0 * __sinf(sp0);
    float cA1 = sa1 * __cosf(sp1),  cB1 = sa1 * __sinf(sp1);
    float cA2 = sa2 * __cosf(sp2v), cB2 = sa2 * __sinf(sp2v);
    float cA3 = sa3 * __cosf(sp3),  cB3 = sa3 * __sinf(sp3);

    // ---- Basis: 3 adjacent column pairs per thread, in registers ----
    const float w0 = TWO_PI / periods[0];
    const float w1 = TWO_PI / periods[1];
    const float w2 = TWO_PI / periods[2];
    const float w3 = TWO_PI / periods[3];

    f32x2 tv[NPAIR];
    f32x2 bs[NPAIR][4], bc[NPAIR][4];
    bool full[NPAIR], any[NPAIR];
    const int t0 = 2 * lane;

    #pragma unroll
    for (int q = 0; q < NPAIR; ++q) {
        const int t = t0 + 128 * q;
        const bool v0 = (t < T), v1 = (t + 1 < T);
        any[q] = v0; full[q] = v1;
        float ta = v0 ? time_vector[t]     : 0.f;
        float tb = v1 ? time_vector[t + 1] : 0.f;
        f32x2 tvp; tvp.x = ta; tvp.y = tb;
        tv[q] = tvp;
        #pragma unroll
        for (int f = 0; f < 4; ++f) {
            const float wf = (f == 0) ? w0 : (f == 1) ? w1 : (f == 2) ? w2 : w3;
            f32x2 s, c;
            s.x = __sinf(wf * ta); s.y = __sinf(wf * tb);
            c.x = __cosf(wf * ta); c.y = __cosf(wf * tb);
            bs[q][f] = s; bc[q][f] = c;
        }
    }

    // ---- Pass 1: store to out (identical to v5/R6) ----
    float* obase = out + (size_t)wbase * T;
    #pragma unroll
    for (int j = 0; j < SPW; ++j) {
        if (j >= send) break;
        float sc  = rlane(cc,  j), sm  = rlane(cm,  j);
        float sA0 = rlane(cA0, j), sB0 = rlane(cB0, j);
        float sA1 = rlane(cA1, j), sB1 = rlane(cB1, j);
        float sA2 = rlane(cA2, j), sB2 = rlane(cB2, j);
        float sA3 = rlane(cA3, j), sB3 = rlane(cB3, j);
        float* orow = obase + (size_t)j * T;

        #pragma unroll
        for (int q = 0; q < NPAIR; ++q) {
            f32x2 sig = sp2(sc) + sp2(sm) * tv[q];
            sig += sp2(sA0) * bs[q][0] + sp2(sB0) * bc[q][0];
            sig += sp2(sA1) * bs[q][1] + sp2(sB1) * bc[q][1];
            sig += sp2(sA2) * bs[q][2] + sp2(sB2) * bc[q][2];
            sig += sp2(sA3) * bs[q][3] + sp2(sB3) * bc[q][3];
            const int t = t0 + 128 * q;
            if (full[q])      store8(orow + t, sig);
            else if (any[q])  orow[t] = sig.x;
        }
    }

    // ---- Pass 2 (slope probe): identical stream into d_ws ----
    if (dw) {
        asm volatile("" ::: "memory");
        float* wbase2 = ws + (size_t)wbase * T;
        #pragma unroll
        for (int j = 0; j < SPW; ++j) {
            if (j >= send) break;
            float sc  = rlane(cc,  j), sm  = rlane(cm,  j);
            float sA0 = rlane(cA0, j), sB0 = rlane(cB0, j);
            float sA1 = rlane(cA1, j), sB1 = rlane(cB1, j);
            float sA2 = rlane(cA2, j), sB2 = rlane(cB2, j);
            float sA3 = rlane(cA3, j), sB3 = rlane(cB3, j);
            float* wrow = wbase2 + (size_t)j * T;

            #pragma unroll
            for (int q = 0; q < NPAIR; ++q) {
                f32x2 sig = sp2(sc) + sp2(sm) * tv[q];
                sig += sp2(sA0) * bs[q][0] + sp2(sB0) * bc[q][0];
                sig += sp2(sA1) * bs[q][1] + sp2(sB1) * bc[q][1];
                sig += sp2(sA2) * bs[q][2] + sp2(sB2) * bc[q][2];
                sig += sp2(sA3) * bs[q][3] + sp2(sB3) * bc[q][3];
                const int t = t0 + 128 * q;
                if (full[q])      store8(wrow + t, sig);
                else if (any[q])  wrow[t] = sig.x;
            }
        }
    }
}

extern "C" void kernel_launch(void* const* d_in, const int* in_sizes, int n_in,
                              void* d_out, int out_size, void* d_ws, size_t ws_size,
                              hipStream_t stream)
{
    const float* time_vector     = (const float*)d_in[0];
    const float* constant_offset = (const float*)d_in[1];
    const float* linear_trend    = (const float*)d_in[2];
    const float* amps            = (const float*)d_in[3];
    const float* phs             = (const float*)d_in[4];
    const float* wgt             = (const float*)d_in[5];
    const float* periods         = (const float*)d_in[6];
    const int*   nbidx           = (const int*)d_in[7];

    int T = in_sizes[0];
    int N = in_sizes[1];
    int K = in_sizes[5] / N;
    float* out = (float*)d_out;

    size_t need = (size_t)N * T * sizeof(float);
    int dw = (ws_size >= need) ? 1 : 0;          // slope probe only if ws fits

    int grid = (N + SPB - 1) / SPB;
    fused_v10<<<grid, BLOCK, 0, stream>>>(
        time_vector, constant_offset, linear_trend, amps, phs, wgt,
        periods, nbidx, out, (float*)d_ws, N, T, K, dw);
}

// Round 12
// 43.625 us; speedup vs baseline: 1.9913x; 1.9913x over previous
//
#include <hip/hip_runtime.h>
#include <math.h>

typedef float f32x2 __attribute__((ext_vector_type(2)));

#define TWO_PI 6.283185307179586f
#define SMOOTH 0.1f
#define SPW 8                  // stations per WAVE
#define WAVES 4
#define BLOCK 256
#define SPB (SPW * WAVES)      // 32 stations per slab; slab = 32*T*4 B = 128*T B
#define NPAIR 3                // column pairs per thread
#define GRID 512               // persistent writer blocks -> marching window = GRID*46.7KB ~ 24MB

__device__ __forceinline__ f32x2 sp2(float x) { f32x2 r; r.x = x; r.y = x; return r; }
__device__ __forceinline__ float rlane(float v, int l) {
    return __uint_as_float((unsigned)__builtin_amdgcn_readlane((int)__float_as_uint(v), l));
}

// ---------------------------------------------------------------------------
// Kernel A: per-station coefficients (R9 structure).
// coef[i][12] = { c, m, A0,B0, A1,B1, A2,B2, A3,B3, 0,0 }
// ---------------------------------------------------------------------------
__global__ void coef_kernel(
    const float* __restrict__ constant_offset,
    const float* __restrict__ linear_trend,
    const float* __restrict__ amps,      // [N][4]
    const float* __restrict__ phs,       // [N][4]
    const float* __restrict__ wgt,       // [N][K]
    const int*   __restrict__ nbidx,     // [N][K]
    float* __restrict__ coef,            // [N][12]
    int N, int K)
{
    int i = blockIdx.x * blockDim.x + threadIdx.x;
    if (i >= N) return;

    float4 a = reinterpret_cast<const float4*>(amps)[i];
    float4 p = reinterpret_cast<const float4*>(phs)[i];

    int   nb[5]; float w[5];
    __builtin_memcpy(nb, nbidx + (size_t)i * K, 5 * sizeof(int));
    __builtin_memcpy(w,  wgt   + (size_t)i * K, 5 * sizeof(float));

    float av0 = 0.f, av1 = 0.f, av2 = 0.f, av3 = 0.f;
    float pv0 = 0.f, pv1 = 0.f, pv2 = 0.f, pv3 = 0.f;
    #pragma unroll
    for (int k = 0; k < 5; ++k) {
        float4 na = reinterpret_cast<const float4*>(amps)[nb[k]];
        float4 np = reinterpret_cast<const float4*>(phs)[nb[k]];
        av0 += w[k] * na.x; av1 += w[k] * na.y; av2 += w[k] * na.z; av3 += w[k] * na.w;
        pv0 += w[k] * np.x; pv1 += w[k] * np.y; pv2 += w[k] * np.z; pv3 += w[k] * np.w;
    }
    float sa0 = (1.0f - SMOOTH) * a.x + SMOOTH * av0;
    float sa1 = (1.0f - SMOOTH) * a.y + SMOOTH * av1;
    float sa2 = (1.0f - SMOOTH) * a.z + SMOOTH * av2;
    float sa3 = (1.0f - SMOOTH) * a.w + SMOOTH * av3;
    float sp0 = (1.0f - SMOOTH) * p.x + SMOOTH * pv0;
    float sp1 = (1.0f - SMOOTH) * p.y + SMOOTH * pv1;
    float sp2 = (1.0f - SMOOTH) * p.z + SMOOTH * pv2;
    float sp3 = (1.0f - SMOOTH) * p.w + SMOOTH * pv3;

    float4 vA, vB, vC;
    vA.x = constant_offset[i]; vA.y = linear_trend[i];
    vA.z = sa0 * __cosf(sp0);  vA.w = sa0 * __sinf(sp0);
    vB.x = sa1 * __cosf(sp1);  vB.y = sa1 * __sinf(sp1);
    vB.z = sa2 * __cosf(sp2);  vB.w = sa2 * __sinf(sp2);
    vC.x = sa3 * __cosf(sp3);  vC.y = sa3 * __sinf(sp3);
    vC.z = 0.f; vC.w = 0.f;
    float4* cp = reinterpret_cast<float4*>(coef + (size_t)i * 12);
    cp[0] = vA; cp[1] = vB; cp[2] = vC;
}

// ---------------------------------------------------------------------------
// Kernel B: PERSISTENT marching writer. GRID blocks grid-stride over slabs so
// the device-wide write stream is a contiguous ~24 MB window marching
// sequentially (the fill kernel's pattern), instead of 3125 one-shot blocks
// scattering ~95 MB of concurrent writes (all prior rounds). Store path per
// slab is R10's: LDS stage + 1024-B-aligned dwordx4 cooperative sweep.
// ---------------------------------------------------------------------------
__global__ __launch_bounds__(BLOCK) void writer_v11(
    const float* __restrict__ time_vector,
    const float* __restrict__ periods,
    const float* __restrict__ coef,      // [N][12]
    float* __restrict__ out,             // [N][T]
    int N, int T, int nslab)
{
    extern __shared__ float slab[];      // SPB * T floats

    const int tid  = threadIdx.x;
    const int wave = tid >> 6;
    const int lane = tid & 63;
    const int t0   = 2 * lane;

    // ---- basis: once, in registers ----
    const float w0 = TWO_PI / periods[0];
    const float w1 = TWO_PI / periods[1];
    const float w2 = TWO_PI / periods[2];
    const float w3 = TWO_PI / periods[3];

    f32x2 tv[NPAIR];
    f32x2 bs[NPAIR][4], bc[NPAIR][4];
    bool full[NPAIR], any[NPAIR];

    #pragma unroll
    for (int q = 0; q < NPAIR; ++q) {
        const int t = t0 + 128 * q;
        const bool v0 = (t < T), v1 = (t + 1 < T);
        any[q] = v0; full[q] = v1;
        float ta = v0 ? time_vector[t]     : 0.f;
        float tb = v1 ? time_vector[t + 1] : 0.f;
        f32x2 tvp; tvp.x = ta; tvp.y = tb;
        tv[q] = tvp;
        #pragma unroll
        for (int f = 0; f < 4; ++f) {
            const float wf = (f == 0) ? w0 : (f == 1) ? w1 : (f == 2) ? w2 : w3;
            f32x2 s, c;
            s.x = __sinf(wf * ta); s.y = __sinf(wf * tb);
            c.x = __cosf(wf * ta); c.y = __cosf(wf * tb);
            bs[q][f] = s; bc[q][f] = c;
        }
    }

    // ---- persistent slab loop (lockstep marching) ----
    for (int i = blockIdx.x; i < nslab; i += GRID) {
        const int bbase  = i * SPB;
        const int wfirst = bbase + wave * SPW;
        const bool fullslab = (bbase + SPB <= N);

        // per-lane coefs for station wfirst+(lane&7)
        int sid = wfirst + (lane & (SPW - 1));
        if (sid >= N) sid = N - 1;
        const float4* cp = reinterpret_cast<const float4*>(coef + (size_t)sid * 12);
        float4 k0 = cp[0];   // c, m, A0, B0
        float4 k1 = cp[1];   // A1, B1, A2, B2
        float4 k2 = cp[2];   // A3, B3, -, -

        int send = N - wfirst; if (send > SPW) send = SPW;

        auto emit_rows = [&](float* rowbase) {
            #pragma unroll
            for (int j = 0; j < SPW; ++j) {
                if (j >= send) break;
                float sc  = rlane(k0.x, j), sm  = rlane(k0.y, j);
                float sA0 = rlane(k0.z, j), sB0 = rlane(k0.w, j);
                float sA1 = rlane(k1.x, j), sB1 = rlane(k1.y, j);
                float sA2 = rlane(k1.z, j), sB2 = rlane(k1.w, j);
                float sA3 = rlane(k2.x, j), sB3 = rlane(k2.y, j);
                float* row = rowbase + (size_t)j * T;
                #pragma unroll
                for (int q = 0; q < NPAIR; ++q) {
                    f32x2 sig = sp2(sc) + sp2(sm) * tv[q];
                    sig += sp2(sA0) * bs[q][0] + sp2(sB0) * bc[q][0];
                    sig += sp2(sA1) * bs[q][1] + sp2(sB1) * bc[q][1];
                    sig += sp2(sA2) * bs[q][2] + sp2(sB2) * bc[q][2];
                    sig += sp2(sA3) * bs[q][3] + sp2(sB3) * bc[q][3];
                    const int t = t0 + 128 * q;
                    if (full[q]) { row[t] = sig.x; row[t + 1] = sig.y; }
                    else if (any[q]) { row[t] = sig.x; }
                }
            }
        };

        if (fullslab) {
            emit_rows(slab + (size_t)(wave * SPW) * T);       // -> LDS
        } else if (send > 0) {
            emit_rows(out + (size_t)wfirst * T);              // tail: direct
        }

        __syncthreads();

        if (fullslab) {
            // 1024-B aligned dwordx4 sweep; slab base byte = i*128*T (128-aligned)
            const float4* lsrc = reinterpret_cast<const float4*>(slab);
            float4* gdst = reinterpret_cast<float4*>(out + (size_t)bbase * T);
            const int nch = (SPB * T) >> 2;                   // 8*T chunks
            for (int c = tid; c < nch; c += BLOCK)
                gdst[c] = lsrc[c];
        }

        __syncthreads();   // protect LDS reuse next iteration
    }
}

extern "C" void kernel_launch(void* const* d_in, const int* in_sizes, int n_in,
                              void* d_out, int out_size, void* d_ws, size_t ws_size,
                              hipStream_t stream)
{
    const float* time_vector     = (const float*)d_in[0];
    const float* constant_offset = (const float*)d_in[1];
    const float* linear_trend    = (const float*)d_in[2];
    const float* amps            = (const float*)d_in[3];
    const float* phs             = (const float*)d_in[4];
    const float* wgt             = (const float*)d_in[5];
    const float* periods         = (const float*)d_in[6];
    const int*   nbidx           = (const int*)d_in[7];

    int T = in_sizes[0];
    int N = in_sizes[1];
    int K = in_sizes[5] / N;
    float* out = (float*)d_out;

    float* coef = (float*)d_ws;                       // 4.8 MB (ws is plenty; R8 verified)

    int gridA = (N + 255) / 256;
    coef_kernel<<<gridA, 256, 0, stream>>>(
        constant_offset, linear_trend, amps, phs, wgt, nbidx, coef, N, K);

    int nslab = (N + SPB - 1) / SPB;
    size_t shmem = (size_t)SPB * T * sizeof(float);   // 46720 B @ T=365
    writer_v11<<<GRID, BLOCK, shmem, stream>>>(
        time_vector, periods, coef, out, N, T, nslab);
}

// Round 13
// 37.650 us; speedup vs baseline: 2.3073x; 1.1587x over previous
//
#include <hip/hip_runtime.h>
#include <math.h>

typedef float f32x2 __attribute__((ext_vector_type(2)));
typedef float f32x4 __attribute__((ext_vector_type(4)));

#define TWO_PI 6.283185307179586f
#define SMOOTH 0.1f
#define SPW 8                  // stations per WAVE
#define WAVES 4
#define BLOCK 256
#define SPB (SPW * WAVES)      // 32 stations per block; slab = 128*T bytes
#define NPAIR 3                // column pairs per thread

__device__ __forceinline__ f32x2 sp2(float x) { f32x2 r; r.x = x; r.y = x; return r; }
__device__ __forceinline__ float rlane(float v, int l) {
    return __uint_as_float((unsigned)__builtin_amdgcn_readlane((int)__float_as_uint(v), l));
}

// v13 = R10's v9 (LDS slab + block-cooperative 128-line-aligned dwordx4
// sweep) with ONE change: the sweep stores are NONTEMPORAL. This is the
// untested corner of the {policy x coverage} matrix:
//   R7  = nt + misaligned dwordx2  (RMW at DRAM -> worse)
//   R10 = cached + full-line x4    (L2 allocate-fetch on store miss -> 2x traffic)
//   v13 = nt + full-line x4        (no allocate, no RMW: the fill's behavior)
__global__ __launch_bounds__(BLOCK) void fused_v13(
    const float* __restrict__ time_vector,
    const float* __restrict__ constant_offset,
    const float* __restrict__ linear_trend,
    const float* __restrict__ amps,      // [N][4]
    const float* __restrict__ phs,       // [N][4]
    const float* __restrict__ wgt,       // [N][K]
    const float* __restrict__ periods,   // [4]
    const int*   __restrict__ nbidx,     // [N][K]
    float* __restrict__ out,             // [N][T]
    int N, int T, int K)
{
    extern __shared__ float slab[];      // SPB * T floats, packed == global layout

    const int tid    = threadIdx.x;
    const int wave   = tid >> 6;
    const int lane   = tid & 63;
    const int bbase  = blockIdx.x * SPB;
    const int wbase  = bbase + wave * SPW;

    if (bbase >= N) return;
    int bsend = N - bbase; if (bsend > SPB) bsend = SPB;

    // ---- Phase 1: coefs for station wbase+(lane&7), all lanes redundant ----
    int sid = wbase + (lane & (SPW - 1));
    if (sid >= N) sid = N - 1;

    float4 a = reinterpret_cast<const float4*>(amps)[sid];
    float4 p = reinterpret_cast<const float4*>(phs)[sid];

    int   nb[5]; float w[5];
    __builtin_memcpy(nb, nbidx + (size_t)sid * K, 5 * sizeof(int));
    __builtin_memcpy(w,  wgt   + (size_t)sid * K, 5 * sizeof(float));

    float av0 = 0.f, av1 = 0.f, av2 = 0.f, av3 = 0.f;
    float pv0 = 0.f, pv1 = 0.f, pv2 = 0.f, pv3 = 0.f;
    #pragma unroll
    for (int k = 0; k < 5; ++k) {
        float4 na = reinterpret_cast<const float4*>(amps)[nb[k]];
        float4 np = reinterpret_cast<const float4*>(phs)[nb[k]];
        av0 += w[k] * na.x; av1 += w[k] * na.y; av2 += w[k] * na.z; av3 += w[k] * na.w;
        pv0 += w[k] * np.x; pv1 += w[k] * np.y; pv2 += w[k] * np.z; pv3 += w[k] * np.w;
    }
    float sa0 = (1.0f - SMOOTH) * a.x + SMOOTH * av0;
    float sa1 = (1.0f - SMOOTH) * a.y + SMOOTH * av1;
    float sa2 = (1.0f - SMOOTH) * a.z + SMOOTH * av2;
    float sa3 = (1.0f - SMOOTH) * a.w + SMOOTH * av3;
    float sp0 = (1.0f - SMOOTH) * p.x + SMOOTH * pv0;
    float sp1 = (1.0f - SMOOTH) * p.y + SMOOTH * pv1;
    float sp2v = (1.0f - SMOOTH) * p.z + SMOOTH * pv2;
    float sp3 = (1.0f - SMOOTH) * p.w + SMOOTH * pv3;

    float cc = constant_offset[sid];
    float cm = linear_trend[sid];
    float cA0 = sa0 * __cosf(sp0),  cB0 = sa0 * __sinf(sp0);
    float cA1 = sa1 * __cosf(sp1),  cB1 = sa1 * __sinf(sp1);
    float cA2 = sa2 * __cosf(sp2v), cB2 = sa2 * __sinf(sp2v);
    float cA3 = sa3 * __cosf(sp3),  cB3 = sa3 * __sinf(sp3);

    // ---- Basis: 3 adjacent column pairs per thread, in registers ----
    const float w0 = TWO_PI / periods[0];
    const float w1 = TWO_PI / periods[1];
    const float w2 = TWO_PI / periods[2];
    const float w3 = TWO_PI / periods[3];

    f32x2 tv[NPAIR];
    f32x2 bs[NPAIR][4], bc[NPAIR][4];
    bool full[NPAIR], any[NPAIR];
    const int t0 = 2 * lane;

    #pragma unroll
    for (int q = 0; q < NPAIR; ++q) {
        const int t = t0 + 128 * q;
        const bool v0 = (t < T), v1 = (t + 1 < T);
        any[q] = v0; full[q] = v1;
        float ta = v0 ? time_vector[t]     : 0.f;
        float tb = v1 ? time_vector[t + 1] : 0.f;
        f32x2 tvp; tvp.x = ta; tvp.y = tb;
        tv[q] = tvp;
        #pragma unroll
        for (int f = 0; f < 4; ++f) {
            const float wf = (f == 0) ? w0 : (f == 1) ? w1 : (f == 2) ? w2 : w3;
            f32x2 s, c;
            s.x = __sinf(wf * ta); s.y = __sinf(wf * tb);
            c.x = __cosf(wf * ta); c.y = __cosf(wf * tb);
            bs[q][f] = s; bc[q][f] = c;
        }
    }

    if (bsend == SPB) {
        // ======== Fast path: LDS slab + full-line nontemporal sweep ========
        float* wrows = slab + (size_t)(wave * SPW) * T;

        #pragma unroll
        for (int j = 0; j < SPW; ++j) {
            float sc  = rlane(cc,  j), sm  = rlane(cm,  j);
            float sA0 = rlane(cA0, j), sB0 = rlane(cB0, j);
            float sA1 = rlane(cA1, j), sB1 = rlane(cB1, j);
            float sA2 = rlane(cA2, j), sB2 = rlane(cB2, j);
            float sA3 = rlane(cA3, j), sB3 = rlane(cB3, j);
            float* lrow = wrows + (size_t)j * T;

            #pragma unroll
            for (int q = 0; q < NPAIR; ++q) {
                f32x2 sig = sp2(sc) + sp2(sm) * tv[q];
                sig += sp2(sA0) * bs[q][0] + sp2(sB0) * bc[q][0];
                sig += sp2(sA1) * bs[q][1] + sp2(sB1) * bc[q][1];
                sig += sp2(sA2) * bs[q][2] + sp2(sB2) * bc[q][2];
                sig += sp2(sA3) * bs[q][3] + sp2(sB3) * bc[q][3];
                const int t = t0 + 128 * q;
                if (full[q]) { lrow[t] = sig.x; lrow[t + 1] = sig.y; }
                else if (any[q]) { lrow[t] = sig.x; }
            }
        }

        __syncthreads();

        // Cooperative sweep: 1024-B aligned wave segments, every 128-B line
        // fully covered by one wave-store — now NONTEMPORAL (no L2 allocate).
        const f32x4* lsrc = reinterpret_cast<const f32x4*>(slab);
        f32x4* gdst = reinterpret_cast<f32x4*>(out + (size_t)bbase * T);
        const int nch = (SPB * T) >> 2;       // 8*T float4 chunks
        for (int i = tid; i < nch; i += BLOCK) {
            f32x4 v = lsrc[i];
            __builtin_nontemporal_store(v, gdst + i);
        }
    } else {
        // ======== Tail path (N % SPB != 0): direct cached stores ========
        int send = N - wbase; if (send > SPW) send = SPW;
        if (send <= 0) return;
        float* obase = out + (size_t)wbase * T;
        for (int j = 0; j < send; ++j) {
            float sc  = rlane(cc,  j), sm  = rlane(cm,  j);
            float sA0 = rlane(cA0, j), sB0 = rlane(cB0, j);
            float sA1 = rlane(cA1, j), sB1 = rlane(cB1, j);
            float sA2 = rlane(cA2, j), sB2 = rlane(cB2, j);
            float sA3 = rlane(cA3, j), sB3 = rlane(cB3, j);
            float* orow = obase + (size_t)j * T;
            #pragma unroll
            for (int q = 0; q < NPAIR; ++q) {
                f32x2 sig = sp2(sc) + sp2(sm) * tv[q];
                sig += sp2(sA0) * bs[q][0] + sp2(sB0) * bc[q][0];
                sig += sp2(sA1) * bs[q][1] + sp2(sB1) * bc[q][1];
                sig += sp2(sA2) * bs[q][2] + sp2(sB2) * bc[q][2];
                sig += sp2(sA3) * bs[q][3] + sp2(sB3) * bc[q][3];
                const int t = t0 + 128 * q;
                if (full[q]) { orow[t] = sig.x; orow[t + 1] = sig.y; }
                else if (any[q]) { orow[t] = sig.x; }
            }
        }
    }
}

extern "C" void kernel_launch(void* const* d_in, const int* in_sizes, int n_in,
                              void* d_out, int out_size, void* d_ws, size_t ws_size,
                              hipStream_t stream)
{
    const float* time_vector     = (const float*)d_in[0];
    const float* constant_offset = (const float*)d_in[1];
    const float* linear_trend    = (const float*)d_in[2];
    const float* amps            = (const float*)d_in[3];
    const float* phs             = (const float*)d_in[4];
    const float* wgt             = (const float*)d_in[5];
    const float* periods         = (const float*)d_in[6];
    const int*   nbidx           = (const int*)d_in[7];

    int T = in_sizes[0];
    int N = in_sizes[1];
    int K = in_sizes[5] / N;
    float* out = (float*)d_out;

    int grid = (N + SPB - 1) / SPB;
    size_t shmem = (size_t)SPB * T * sizeof(float);    // 46720 B @ T=365
    fused_v13<<<grid, BLOCK, shmem, stream>>>(
        time_vector, constant_offset, linear_trend, amps, phs, wgt,
        periods, nbidx, out, N, T, K);
}

// Round 14
// 35.770 us; speedup vs baseline: 2.4286x; 1.0525x over previous
//
#include <hip/hip_runtime.h>
#include <math.h>

typedef float f32x2 __attribute__((ext_vector_type(2)));
typedef float f32x4 __attribute__((ext_vector_type(4)));

#define TWO_PI 6.283185307179586f
#define SMOOTH 0.1f
#define SPW 8                  // stations per WAVE
#define WAVES 4
#define BLOCK 256
#define SPB (SPW * WAVES)      // 32 stations; slab = 128*T bytes (line-integral)
#define NPAIR 3                // column pairs per thread

__device__ __forceinline__ f32x2 sp2(float x) { f32x2 r; r.x = x; r.y = x; return r; }
__device__ __forceinline__ float rlane(float v, int l) {
    return __uint_as_float((unsigned)__builtin_amdgcn_readlane((int)__float_as_uint(v), l));
}

// v14 = v13 (LDS slab + full-line NONTEMPORAL dwordx4 sweep) with the sweep
// restructured for fill-identical store-issue density:
//   - compile-time T (template) -> static trip counts, folded addressing,
//     mergeable LDS writes, branchless q-predicates
//   - register-batched sweep: ALL ds_read_b128 issued back-to-back, one
//     lgkm drain, then ALL nt stores back-to-back (no per-store DS latency)
template<int TT>
__global__ __launch_bounds__(BLOCK) void fused_v14(
    const float* __restrict__ time_vector,
    const float* __restrict__ constant_offset,
    const float* __restrict__ linear_trend,
    const float* __restrict__ amps,      // [N][4]
    const float* __restrict__ phs,       // [N][4]
    const float* __restrict__ wgt,       // [N][K]
    const float* __restrict__ periods,   // [4]
    const int*   __restrict__ nbidx,     // [N][K]
    float* __restrict__ out,             // [N][T]
    int N, int T_rt, int K)
{
    const int T = (TT > 0) ? TT : T_rt;          // folds when TT=365
    extern __shared__ float slab[];              // SPB * T floats

    const int tid    = threadIdx.x;
    const int wave   = tid >> 6;
    const int lane   = tid & 63;
    const int bbase  = blockIdx.x * SPB;
    const int wbase  = bbase + wave * SPW;

    if (bbase >= N) return;
    int bsend = N - bbase; if (bsend > SPB) bsend = SPB;

    // ---- Phase 1: coefs for station wbase+(lane&7), all lanes redundant ----
    int sid = wbase + (lane & (SPW - 1));
    if (sid >= N) sid = N - 1;

    float4 a = reinterpret_cast<const float4*>(amps)[sid];
    float4 p = reinterpret_cast<const float4*>(phs)[sid];

    int   nb[5]; float w[5];
    __builtin_memcpy(nb, nbidx + (size_t)sid * K, 5 * sizeof(int));
    __builtin_memcpy(w,  wgt   + (size_t)sid * K, 5 * sizeof(float));

    float av0 = 0.f, av1 = 0.f, av2 = 0.f, av3 = 0.f;
    float pv0 = 0.f, pv1 = 0.f, pv2 = 0.f, pv3 = 0.f;
    #pragma unroll
    for (int k = 0; k < 5; ++k) {
        float4 na = reinterpret_cast<const float4*>(amps)[nb[k]];
        float4 np = reinterpret_cast<const float4*>(phs)[nb[k]];
        av0 += w[k] * na.x; av1 += w[k] * na.y; av2 += w[k] * na.z; av3 += w[k] * na.w;
        pv0 += w[k] * np.x; pv1 += w[k] * np.y; pv2 += w[k] * np.z; pv3 += w[k] * np.w;
    }
    float sa0 = (1.0f - SMOOTH) * a.x + SMOOTH * av0;
    float sa1 = (1.0f - SMOOTH) * a.y + SMOOTH * av1;
    float sa2 = (1.0f - SMOOTH) * a.z + SMOOTH * av2;
    float sa3 = (1.0f - SMOOTH) * a.w + SMOOTH * av3;
    float sp0 = (1.0f - SMOOTH) * p.x + SMOOTH * pv0;
    float sp1 = (1.0f - SMOOTH) * p.y + SMOOTH * pv1;
    float sp2v = (1.0f - SMOOTH) * p.z + SMOOTH * pv2;
    float sp3 = (1.0f - SMOOTH) * p.w + SMOOTH * pv3;

    float cc = constant_offset[sid];
    float cm = linear_trend[sid];
    float cA0 = sa0 * __cosf(sp0),  cB0 = sa0 * __sinf(sp0);
    float cA1 = sa1 * __cosf(sp1),  cB1 = sa1 * __sinf(sp1);
    float cA2 = sa2 * __cosf(sp2v), cB2 = sa2 * __sinf(sp2v);
    float cA3 = sa3 * __cosf(sp3),  cB3 = sa3 * __sinf(sp3);

    // ---- Basis: 3 adjacent column pairs per thread, in registers ----
    const float w0 = TWO_PI / periods[0];
    const float w1 = TWO_PI / periods[1];
    const float w2 = TWO_PI / periods[2];
    const float w3 = TWO_PI / periods[3];

    f32x2 tv[NPAIR];
    f32x2 bs[NPAIR][4], bc[NPAIR][4];
    bool full[NPAIR], any[NPAIR];
    const int t0 = 2 * lane;

    #pragma unroll
    for (int q = 0; q < NPAIR; ++q) {
        const int t = t0 + 128 * q;
        const bool v0 = (t < T), v1 = (t + 1 < T);
        any[q] = v0; full[q] = v1;
        float ta = v0 ? time_vector[t]     : 0.f;
        float tb = v1 ? time_vector[t + 1] : 0.f;
        f32x2 tvp; tvp.x = ta; tvp.y = tb;
        tv[q] = tvp;
        #pragma unroll
        for (int f = 0; f < 4; ++f) {
            const float wf = (f == 0) ? w0 : (f == 1) ? w1 : (f == 2) ? w2 : w3;
            f32x2 s, c;
            s.x = __sinf(wf * ta); s.y = __sinf(wf * tb);
            c.x = __cosf(wf * ta); c.y = __cosf(wf * tb);
            bs[q][f] = s; bc[q][f] = c;
        }
    }

    if (bsend == SPB) {
        // ======== Fast path: stage slab, then register-batched nt sweep ====
        float* wrows = slab + (size_t)(wave * SPW) * T;

        #pragma unroll
        for (int j = 0; j < SPW; ++j) {
            float sc  = rlane(cc,  j), sm  = rlane(cm,  j);
            float sA0 = rlane(cA0, j), sB0 = rlane(cB0, j);
            float sA1 = rlane(cA1, j), sB1 = rlane(cB1, j);
            float sA2 = rlane(cA2, j), sB2 = rlane(cB2, j);
            float sA3 = rlane(cA3, j), sB3 = rlane(cB3, j);
            float* lrow = wrows + j * T;          // const offset when TT>0

            #pragma unroll
            for (int q = 0; q < NPAIR; ++q) {
                f32x2 sig = sp2(sc) + sp2(sm) * tv[q];
                sig += sp2(sA0) * bs[q][0] + sp2(sB0) * bc[q][0];
                sig += sp2(sA1) * bs[q][1] + sp2(sB1) * bc[q][1];
                sig += sp2(sA2) * bs[q][2] + sp2(sB2) * bc[q][2];
                sig += sp2(sA3) * bs[q][3] + sp2(sB3) * bc[q][3];
                const int t = t0 + 128 * q;
                if (full[q]) { lrow[t] = sig.x; lrow[t + 1] = sig.y; }
                else if (any[q]) { lrow[t] = sig.x; }
            }
        }

        __syncthreads();

        // Register-batched sweep: all LDS reads first, one drain, then all
        // nt stores back-to-back (fill-identical issue pattern).
        const f32x4* lsrc = reinterpret_cast<const f32x4*>(slab);
        f32x4* gdst = reinterpret_cast<f32x4*>(out + (size_t)bbase * T);

        if (TT == 365) {
            // nch = 32*365/4 = 2920 = 11*256 + 104  (static)
            f32x4 v0_ = lsrc[tid];          f32x4 v1_ = lsrc[tid + 256];
            f32x4 v2_ = lsrc[tid + 512];    f32x4 v3_ = lsrc[tid + 768];
            f32x4 v4_ = lsrc[tid + 1024];   f32x4 v5_ = lsrc[tid + 1280];
            f32x4 v6_ = lsrc[tid + 1536];   f32x4 v7_ = lsrc[tid + 1792];
            f32x4 v8_ = lsrc[tid + 2048];   f32x4 v9_ = lsrc[tid + 2304];
            f32x4 va_ = lsrc[tid + 2560];
            const bool extra = (tid < 104);
            f32x4 vb_;
            if (extra) vb_ = lsrc[tid + 2816];

            __builtin_nontemporal_store(v0_, gdst + tid);
            __builtin_nontemporal_store(v1_, gdst + tid + 256);
            __builtin_nontemporal_store(v2_, gdst + tid + 512);
            __builtin_nontemporal_store(v3_, gdst + tid + 768);
            __builtin_nontemporal_store(v4_, gdst + tid + 1024);
            __builtin_nontemporal_store(v5_, gdst + tid + 1280);
            __builtin_nontemporal_store(v6_, gdst + tid + 1536);
            __builtin_nontemporal_store(v7_, gdst + tid + 1792);
            __builtin_nontemporal_store(v8_, gdst + tid + 2048);
            __builtin_nontemporal_store(v9_, gdst + tid + 2304);
            __builtin_nontemporal_store(va_, gdst + tid + 2560);
            if (extra) __builtin_nontemporal_store(vb_, gdst + tid + 2816);
        } else {
            const int nch = (SPB * T) >> 2;
            for (int i = tid; i < nch; i += BLOCK) {
                f32x4 v = lsrc[i];
                __builtin_nontemporal_store(v, gdst + i);
            }
        }
    } else {
        // ======== Tail path: direct cached stores ========
        int send = N - wbase; if (send > SPW) send = SPW;
        if (send <= 0) return;
        float* obase = out + (size_t)wbase * T;
        for (int j = 0; j < send; ++j) {
            float sc  = rlane(cc,  j), sm  = rlane(cm,  j);
            float sA0 = rlane(cA0, j), sB0 = rlane(cB0, j);
            float sA1 = rlane(cA1, j), sB1 = rlane(cB1, j);
            float sA2 = rlane(cA2, j), sB2 = rlane(cB2, j);
            float sA3 = rlane(cA3, j), sB3 = rlane(cB3, j);
            float* orow = obase + (size_t)j * T;
            #pragma unroll
            for (int q = 0; q < NPAIR; ++q) {
                f32x2 sig = sp2(sc) + sp2(sm) * tv[q];
                sig += sp2(sA0) * bs[q][0] + sp2(sB0) * bc[q][0];
                sig += sp2(sA1) * bs[q][1] + sp2(sB1) * bc[q][1];
                sig += sp2(sA2) * bs[q][2] + sp2(sB2) * bc[q][2];
                sig += sp2(sA3) * bs[q][3] + sp2(sB3) * bc[q][3];
                const int t = t0 + 128 * q;
                if (full[q]) { orow[t] = sig.x; orow[t + 1] = sig.y; }
                else if (any[q]) { orow[t] = sig.x; }
            }
        }
    }
}

extern "C" void kernel_launch(void* const* d_in, const int* in_sizes, int n_in,
                              void* d_out, int out_size, void* d_ws, size_t ws_size,
                              hipStream_t stream)
{
    const float* time_vector     = (const float*)d_in[0];
    const float* constant_offset = (const float*)d_in[1];
    const float* linear_trend    = (const float*)d_in[2];
    const float* amps            = (const float*)d_in[3];
    const float* phs             = (const float*)d_in[4];
    const float* wgt             = (const float*)d_in[5];
    const float* periods         = (const float*)d_in[6];
    const int*   nbidx           = (const int*)d_in[7];

    int T = in_sizes[0];
    int N = in_sizes[1];
    int K = in_sizes[5] / N;
    float* out = (float*)d_out;

    int grid = (N + SPB - 1) / SPB;
    size_t shmem = (size_t)SPB * T * sizeof(float);
    if (T == 365) {
        fused_v14<365><<<grid, BLOCK, shmem, stream>>>(
            time_vector, constant_offset, linear_trend, amps, phs, wgt,
            periods, nbidx, out, N, T, K);
    } else {
        fused_v14<0><<<grid, BLOCK, shmem, stream>>>(
            time_vector, constant_offset, linear_trend, amps, phs, wgt,
            periods, nbidx, out, N, T, K);
    }
}